// Round 4
// baseline (418.797 us; speedup 1.0000x reference)
//
#include <hip/hip_runtime.h>

#define NMOV 100000
#define NUSR 50000
#define NN   150000
#define DIM  128
#define HID  256
#define NE   500000

#define MBLK 128           // rows per block
#define LDK  264           // LDS row stride in shorts for the A/h tile
#define NB_SCAN ((NN + 255) / 256)   // 586

typedef __attribute__((ext_vector_type(8))) short bf16x8;
typedef __attribute__((ext_vector_type(4))) float f32x4;

__device__ __forceinline__ short f2bf(float f) {
  union { float f; unsigned u; } v; v.f = f;
  unsigned r = (v.u + 0x7fffu + ((v.u >> 16) & 1u)) >> 16;   // RNE
  return (short)r;
}
__device__ __forceinline__ float bf2f(short s) {
  union { unsigned u; float f; } v;
  v.u = ((unsigned)(unsigned short)s) << 16;
  return v.f;
}

// ================= CSR build =================
__global__ __launch_bounds__(256) void deg_kernel(const int* __restrict__ dst,
                                                  int* __restrict__ degi) {
  int e = blockIdx.x * 256 + threadIdx.x;
  if (e < NE) atomicAdd(&degi[dst[e]], 1);
}

__global__ __launch_bounds__(256) void scan1_kernel(const int* __restrict__ degi,
                                                    int* __restrict__ pre,
                                                    int* __restrict__ bsum) {
  __shared__ int s[256];
  int tid = threadIdx.x;
  int i = blockIdx.x * 256 + tid;
  int v = (i < NN) ? degi[i] : 0;
  s[tid] = v;
  __syncthreads();
#pragma unroll
  for (int off = 1; off < 256; off <<= 1) {
    int t = (tid >= off) ? s[tid - off] : 0;
    __syncthreads();
    s[tid] += t;
    __syncthreads();
  }
  if (i < NN) pre[i] = s[tid] - v;
  if (tid == 255) bsum[blockIdx.x] = s[255];
}

// merged scan2+scan3: each block reduces its own bsum prefix, then writes rowptr
__global__ __launch_bounds__(256) void scan23_kernel(const int* __restrict__ pre,
                                                     const int* __restrict__ bsum,
                                                     int* __restrict__ rowptr) {
  __shared__ int sm[256];
  int tid = threadIdx.x;
  int nb = blockIdx.x;
  int v = 0;
  for (int i = tid; i < nb; i += 256) v += bsum[i];   // <=3 iters
  sm[tid] = v;
  __syncthreads();
#pragma unroll
  for (int off = 128; off > 0; off >>= 1) {
    if (tid < off) sm[tid] += sm[tid + off];
    __syncthreads();
  }
  int base = sm[0];
  int i = nb * 256 + tid;
  if (i < NN) rowptr[i] = pre[i] + base;
  if (i == 0) rowptr[NN] = NE;
}

// stores SRC node id per CSR slot (single indirection in the gathers)
__global__ __launch_bounds__(256) void csr_scatter_kernel(const int* __restrict__ src,
                                                          const int* __restrict__ dst,
                                                          const int* __restrict__ rowptr,
                                                          int* __restrict__ cnt,
                                                          int* __restrict__ esrc) {
  int e = blockIdx.x * 256 + threadIdx.x;
  if (e >= NE) return;
  int d = dst[e];
  int pos = rowptr[d] + atomicAdd(&cnt[d], 1);
  esrc[pos] = src[e];
}

// second scatter (after gather2, into dead hWb region): (src, eid) pairs for score
__global__ __launch_bounds__(256) void scatter2_kernel(const int* __restrict__ src,
                                                       const int* __restrict__ dst,
                                                       const int* __restrict__ rowptr,
                                                       int* __restrict__ cnt2,
                                                       int2* __restrict__ epk) {
  int e = blockIdx.x * 256 + threadIdx.x;
  if (e >= NE) return;
  int d = dst[e];
  int pos = rowptr[d] + atomicAdd(&cnt2[d], 1);
  epk[pos] = make_int2(src[e], e);
}

// ================= bf16 conversion of node features =================
__global__ __launch_bounds__(256) void convx_kernel(const float* __restrict__ movie,
                                                    const float* __restrict__ user,
                                                    short* __restrict__ xb) {
  int c = blockIdx.x * 256 + threadIdx.x;        // chunk of 8
  if (c >= NN * DIM / 8) return;
  size_t base = (size_t)c * 8;
  const float* srcp = (base < (size_t)NMOV * DIM) ? (movie + base)
                                                  : (user + (base - (size_t)NMOV * DIM));
  float4 v0 = ((const float4*)srcp)[0];
  float4 v1 = ((const float4*)srcp)[1];
  short4 s0 = make_short4(f2bf(v0.x), f2bf(v0.y), f2bf(v0.z), f2bf(v0.w));
  short4 s1 = make_short4(f2bf(v1.x), f2bf(v1.y), f2bf(v1.z), f2bf(v1.w));
  *(short4*)(xb + base)     = s0;
  *(short4*)(xb + base + 4) = s1;
}

// ================= weight swizzle: bf16, MFMA-fragment-linear =================
__global__ __launch_bounds__(256) void convw_kernel(const float* __restrict__ Wl1,
                                                    const float* __restrict__ Wr1,
                                                    const float* __restrict__ Wl2,
                                                    const float* __restrict__ Wr2,
                                                    short* __restrict__ Wf1,
                                                    short* __restrict__ Wf2) {
  int t = blockIdx.x * 256 + threadIdx.x;   // 2*16*8*64 = 16384 threads
  int stage = t >> 13;
  int r = t & 8191;
  int n    = r >> 9;
  int kk   = (r >> 6) & 7;
  int lane = r & 63;
  int ncol  = n * 16 + (lane & 15);
  int kbase = kk * 32 + (lane >> 4) * 8;
  short vals[8];
#pragma unroll
  for (int jj = 0; jj < 8; jj++) {
    int k = kbase + jj;
    float v;
    if (stage == 0)
      v = (k < 128) ? Wl1[(size_t)k * HID + ncol] : Wr1[(size_t)(k - 128) * HID + ncol];
    else
      v = (ncol < 128) ? Wl2[(size_t)k * DIM + ncol] : Wr2[(size_t)k * DIM + (ncol - 128)];
    vals[jj] = f2bf(v);
  }
  short* outp = (stage == 0 ? Wf1 : Wf2) + ((size_t)(n * 8 + kk) << 9) + lane * 8;
  *(short4*)(outp)     = make_short4(vals[0], vals[1], vals[2], vals[3]);
  *(short4*)(outp + 4) = make_short4(vals[4], vals[5], vals[6], vals[7]);
}

// ================= gather1: aggb[node] = bf16(mean of xb[src rows]) =================
__global__ __launch_bounds__(256) void gather1_kernel(const int* __restrict__ rowptr,
                                                      const int* __restrict__ esrc,
                                                      const short* __restrict__ xb,
                                                      short* __restrict__ aggb) {
  int t = blockIdx.x * 256 + threadIdx.x;
  int node = t >> 4, l = t & 15;
  if (node >= NN) return;
  int b = rowptr[node], e = rowptr[node + 1];
  float acc[8] = {0.f, 0.f, 0.f, 0.f, 0.f, 0.f, 0.f, 0.f};
  for (int j = b; j < e; j += 4) {
    int i1 = (j + 1 < e) ? j + 1 : j;
    int i2 = (j + 2 < e) ? j + 2 : j;
    int i3 = (j + 3 < e) ? j + 3 : j;
    int s0 = esrc[j], s1 = esrc[i1], s2 = esrc[i2], s3 = esrc[i3];
    bf16x8 r0 = *(const bf16x8*)(xb + (size_t)s0 * DIM + l * 8);
    bf16x8 r1 = *(const bf16x8*)(xb + (size_t)s1 * DIM + l * 8);
    bf16x8 r2 = *(const bf16x8*)(xb + (size_t)s2 * DIM + l * 8);
    bf16x8 r3 = *(const bf16x8*)(xb + (size_t)s3 * DIM + l * 8);
    float m1 = (j + 1 < e) ? 1.f : 0.f;
    float m2 = (j + 2 < e) ? 1.f : 0.f;
    float m3 = (j + 3 < e) ? 1.f : 0.f;
#pragma unroll
    for (int k = 0; k < 8; k++)
      acc[k] += bf2f(r0[k]) + m1 * bf2f(r1[k]) + m2 * bf2f(r2[k]) + m3 * bf2f(r3[k]);
  }
  float inv = 1.0f / fmaxf((float)(e - b), 1.0f);
  bf16x8 ov;
#pragma unroll
  for (int k = 0; k < 8; k++) ov[k] = f2bf(acc[k] * inv);
  *(bf16x8*)(aggb + (size_t)node * DIM + l * 8) = ov;
}

// ================= fused MFMA: both GEMMs, h stays in LDS =================
// 512 threads = 8 thin waves; each wave owns 32 rows x 128 cols.
// unroll 2 on the nn loops lets the scheduler hoist next-n weight loads
// above the current MFMA cluster (compiler-scheduled prefetch).
__global__ __launch_bounds__(512, 4) void fused_mfma_kernel(
    short* xb_drefp, short* ab_hw,
    const short* __restrict__ Wf1, const float* __restrict__ bl1,
    const short* __restrict__ Wf2, const float* __restrict__ bl2) {
  __shared__ __align__(16) short tile[MBLK][LDK];   // 67.6 KB -> 2 blocks/CU
  const int tid = threadIdx.x;
  const int row0 = blockIdx.x * MBLK;

  // stage A_cat = [aggb | xb] bf16, 16B chunks
  for (int idx = tid; idx < MBLK * 32; idx += 512) {
    int r   = idx >> 5;
    int c16 = idx & 31;
    int row = row0 + r;
    int col = c16 * 8;
    int4 v = make_int4(0, 0, 0, 0);
    if (row < NN) {
      const short* srcp = (col < DIM) ? (ab_hw + (size_t)row * DIM + col)
                                      : (xb_drefp + (size_t)row * DIM + (col - DIM));
      v = *(const int4*)srcp;
    }
    *(int4*)&tile[r][col] = v;
  }
  __syncthreads();

  const int lane = tid & 63;
  const int wv   = tid >> 6;          // 0..7
  const int c    = lane & 15;
  const int quad = lane >> 4;
  const int wrow = (wv & 3) * 32;     // row quarter (32 rows = 2 groups of 16)
  const int ch   = wv >> 2;           // col half

  // ---- stage 1: h = relu(A_cat @ W1 + bl1) -> LDS ----
  {
    bf16x8 af[2][8];
#pragma unroll
    for (int rg = 0; rg < 2; rg++)
#pragma unroll
      for (int kk = 0; kk < 8; kk++)
        af[rg][kk] = *(const bf16x8*)&tile[wrow + rg * 16 + c][kk * 32 + quad * 8];
    __syncthreads();                  // A in regs everywhere -> safe to overwrite tile

#pragma unroll 2
    for (int nn = 0; nn < 8; nn++) {
      int n = ch * 8 + nn;
      const short* wq = Wf1 + ((size_t)(n * 8) << 9) + lane * 8;
      bf16x8 bw[8];
#pragma unroll
      for (int kk = 0; kk < 8; kk++)
        bw[kk] = *(const bf16x8*)(wq + ((size_t)kk << 9));
      f32x4 a0 = {0.f, 0.f, 0.f, 0.f}, a1 = {0.f, 0.f, 0.f, 0.f};
      __builtin_amdgcn_s_setprio(1);
#pragma unroll
      for (int kk = 0; kk < 8; kk++) {
        a0 = __builtin_amdgcn_mfma_f32_16x16x32_bf16(af[0][kk], bw[kk], a0, 0, 0, 0);
        a1 = __builtin_amdgcn_mfma_f32_16x16x32_bf16(af[1][kk], bw[kk], a1, 0, 0, 0);
      }
      __builtin_amdgcn_s_setprio(0);
      float bv = bl1[n * 16 + c];
#pragma unroll
      for (int i = 0; i < 4; i++) {
        tile[wrow +      quad * 4 + i][n * 16 + c] = f2bf(fmaxf(a0[i] + bv, 0.0f));
        tile[wrow + 16 + quad * 4 + i][n * 16 + c] = f2bf(fmaxf(a1[i] + bv, 0.0f));
      }
    }
  }
  __syncthreads();

  // ---- stage 2: [hW | h@Wr2+bl2] -> tile (both halves), then stream out ----
  {
    bf16x8 af[2][8];
#pragma unroll
    for (int rg = 0; rg < 2; rg++)
#pragma unroll
      for (int kk = 0; kk < 8; kk++)
        af[rg][kk] = *(const bf16x8*)&tile[wrow + rg * 16 + c][kk * 32 + quad * 8];
    __syncthreads();                   // all waves done reading h -> safe to overwrite

#pragma unroll 2
    for (int nn = 0; nn < 8; nn++) {
      int n = ch * 8 + nn;
      const short* wq = Wf2 + ((size_t)(n * 8) << 9) + lane * 8;
      bf16x8 bw[8];
#pragma unroll
      for (int kk = 0; kk < 8; kk++)
        bw[kk] = *(const bf16x8*)(wq + ((size_t)kk << 9));
      f32x4 a0 = {0.f, 0.f, 0.f, 0.f}, a1 = {0.f, 0.f, 0.f, 0.f};
      __builtin_amdgcn_s_setprio(1);
#pragma unroll
      for (int kk = 0; kk < 8; kk++) {
        a0 = __builtin_amdgcn_mfma_f32_16x16x32_bf16(af[0][kk], bw[kk], a0, 0, 0, 0);
        a1 = __builtin_amdgcn_mfma_f32_16x16x32_bf16(af[1][kk], bw[kk], a1, 0, 0, 0);
      }
      __builtin_amdgcn_s_setprio(0);
      int col = n * 16 + c;
      float bv = (ch == 1) ? bl2[col - 128] : 0.0f;   // bias only on the Wr2 half
#pragma unroll
      for (int i = 0; i < 4; i++) {
        tile[wrow +      quad * 4 + i][col] = f2bf(a0[i] + bv);
        tile[wrow + 16 + quad * 4 + i][col] = f2bf(a1[i] + bv);
      }
    }
  }
  __syncthreads();

  // stream both halves out coalesced (b128 chunks)
  for (int idx = tid; idx < MBLK * 32; idx += 512) {
    int r   = idx >> 5;
    int c16 = idx & 31;
    int row = row0 + r;
    if (row < NN) {
      int4 v = *(const int4*)&tile[r][c16 * 8];
      if (c16 < 16)
        *(int4*)(ab_hw + (size_t)row * DIM + c16 * 8) = v;
      else
        *(int4*)(xb_drefp + (size_t)row * DIM + (c16 - 16) * 8) = v;
    }
  }
}

// ================= gather2: dref = partial + mean(hWb[src]); bf16 shadow in place ====
__global__ __launch_bounds__(256) void gather2_kernel(const int* __restrict__ rowptr,
                                                      const int* __restrict__ esrc,
                                                      const short* __restrict__ hWb,
                                                      short* xbuf,
                                                      float* __restrict__ dref) {
  int t = blockIdx.x * 256 + threadIdx.x;
  int node = t >> 4, l = t & 15;
  if (node >= NN) return;
  int b = rowptr[node], e = rowptr[node + 1];
  bf16x8 p = *(const bf16x8*)(xbuf + (size_t)node * DIM + l * 8);  // hoisted partial
  float acc[8] = {0.f, 0.f, 0.f, 0.f, 0.f, 0.f, 0.f, 0.f};
  for (int j = b; j < e; j += 4) {
    int i1 = (j + 1 < e) ? j + 1 : j;
    int i2 = (j + 2 < e) ? j + 2 : j;
    int i3 = (j + 3 < e) ? j + 3 : j;
    int s0 = esrc[j], s1 = esrc[i1], s2 = esrc[i2], s3 = esrc[i3];
    bf16x8 r0 = *(const bf16x8*)(hWb + (size_t)s0 * DIM + l * 8);
    bf16x8 r1 = *(const bf16x8*)(hWb + (size_t)s1 * DIM + l * 8);
    bf16x8 r2 = *(const bf16x8*)(hWb + (size_t)s2 * DIM + l * 8);
    bf16x8 r3 = *(const bf16x8*)(hWb + (size_t)s3 * DIM + l * 8);
    float m1 = (j + 1 < e) ? 1.f : 0.f;
    float m2 = (j + 2 < e) ? 1.f : 0.f;
    float m3 = (j + 3 < e) ? 1.f : 0.f;
#pragma unroll
    for (int k = 0; k < 8; k++)
      acc[k] += bf2f(r0[k]) + m1 * bf2f(r1[k]) + m2 * bf2f(r2[k]) + m3 * bf2f(r3[k]);
  }
  float inv = 1.0f / fmaxf((float)(e - b), 1.0f);
  float fin[8];
  bf16x8 ov;
#pragma unroll
  for (int k = 0; k < 8; k++) {
    fin[k] = bf2f(p[k]) + acc[k] * inv;
    ov[k] = f2bf(fin[k]);
  }
  float* dr = dref + (size_t)node * DIM + l * 8;
  *(float4*)(dr)     = make_float4(fin[0], fin[1], fin[2], fin[3]);
  *(float4*)(dr + 4) = make_float4(fin[4], fin[5], fin[6], fin[7]);
  *(bf16x8*)(xbuf + (size_t)node * DIM + l * 8) = ov;
}

// ================= edge scoring, CSR-node-parallel, dst row in regs =================
__global__ __launch_bounds__(256) void score_kernel(const int* __restrict__ rowptr,
                                                    const int2* __restrict__ epk,
                                                    const short* __restrict__ drefb,
                                                    float* __restrict__ out) {
  int t = blockIdx.x * 256 + threadIdx.x;
  int node = t >> 4, l = t & 15;
  if (node >= NN) return;
  int b = rowptr[node], e = rowptr[node + 1];
  if (b == e) return;
  bf16x8 d = *(const bf16x8*)(drefb + (size_t)node * DIM + l * 8);
  float f[8];
#pragma unroll
  for (int k = 0; k < 8; k++) f[k] = bf2f(d[k]);
  for (int j = b; j < e; j += 4) {
    int i1 = (j + 1 < e) ? j + 1 : j;
    int i2 = (j + 2 < e) ? j + 2 : j;
    int i3 = (j + 3 < e) ? j + 3 : j;
    int2 p0 = epk[j], p1 = epk[i1], p2 = epk[i2], p3 = epk[i3];
    bf16x8 r0 = *(const bf16x8*)(drefb + (size_t)p0.x * DIM + l * 8);
    bf16x8 r1 = *(const bf16x8*)(drefb + (size_t)p1.x * DIM + l * 8);
    bf16x8 r2 = *(const bf16x8*)(drefb + (size_t)p2.x * DIM + l * 8);
    bf16x8 r3 = *(const bf16x8*)(drefb + (size_t)p3.x * DIM + l * 8);
    float s0 = 0.f, s1 = 0.f, s2 = 0.f, s3 = 0.f;
#pragma unroll
    for (int k = 0; k < 8; k++) {
      s0 += bf2f(r0[k]) * f[k];
      s1 += bf2f(r1[k]) * f[k];
      s2 += bf2f(r2[k]) * f[k];
      s3 += bf2f(r3[k]) * f[k];
    }
#pragma unroll
    for (int off = 1; off < 16; off <<= 1) {
      s0 += __shfl_xor(s0, off, 16);
      s1 += __shfl_xor(s1, off, 16);
      s2 += __shfl_xor(s2, off, 16);
      s3 += __shfl_xor(s3, off, 16);
    }
    if (l == 0) {
      out[p0.y] = s0;
      if (j + 1 < e) out[p1.y] = s1;
      if (j + 2 < e) out[p2.y] = s2;
      if (j + 3 < e) out[p3.y] = s3;
    }
  }
}

extern "C" void kernel_launch(void* const* d_in, const int* in_sizes, int n_in,
                              void* d_out, int out_size, void* d_ws, size_t ws_size,
                              hipStream_t stream) {
  const int* ei    = (const int*)d_in[0];
  const int* src   = ei;
  const int* dst   = ei + NE;
  // d_in[1] = edge_attr (unused by the reference)
  const float* movie = (const float*)d_in[2];
  const float* user  = (const float*)d_in[3];
  const float* Wl1   = (const float*)d_in[4];
  const float* bl1   = (const float*)d_in[5];
  const float* Wr1   = (const float*)d_in[6];
  const float* Wl2   = (const float*)d_in[7];
  const float* bl2   = (const float*)d_in[8];
  const float* Wr2   = (const float*)d_in[9];

  float* out  = (float*)d_out;       // [NE] ratings
  float* dref = out + NE;            // [NN*DIM] refined (f32 output)

  // workspace (~81.6 MB): ints | xb(+drefb alias) | aggb(+hWb+epk alias) | Wf1 | Wf2
  int* degi   = (int*)d_ws;                    // [NN] (zeroed)
  int* cnt    = degi + NN;                     // [NN] (zeroed; re-zeroed for scatter2)
  int* pre    = cnt + NN;                      // [NN]
  int* bsum   = pre + NN;                      // [1024]
  int* rowptr = bsum + 1024;                   // [NN+1]
  int* esrc   = rowptr + NN + 1;               // [NE] src node per CSR slot
  short* xb   = (short*)(((uintptr_t)(esrc + NE) + 15) & ~(uintptr_t)15);  // [NN*DIM] bf16
  short* aggb = xb + (size_t)NN * DIM;         // [NN*DIM] bf16 (later hWb, then epk)
  short* Wf1  = aggb + (size_t)NN * DIM;       // [65536]
  short* Wf2  = Wf1 + 65536;                   // [65536]
  short* hWb   = aggb;                         // alias: fused overwrites its own rows
  int2*  epk   = (int2*)aggb;                  // alias: hWb dead after gather2
  // xb aliases: partial (h@Wr2+bl2, by fused) then final bf16 shadow (gather2)

  hipMemsetAsync(degi, 0, (size_t)2 * NN * sizeof(int), stream);

  deg_kernel<<<(NE + 255) / 256, 256, 0, stream>>>(dst, degi);
  scan1_kernel<<<NB_SCAN, 256, 0, stream>>>(degi, pre, bsum);
  scan23_kernel<<<NB_SCAN, 256, 0, stream>>>(pre, bsum, rowptr);
  csr_scatter_kernel<<<(NE + 255) / 256, 256, 0, stream>>>(src, dst, rowptr, cnt, esrc);
  hipMemsetAsync(cnt, 0, (size_t)NN * sizeof(int), stream);   // cnt -> cnt2 for scatter2
  convx_kernel<<<NN * DIM / 8 / 256, 256, 0, stream>>>(movie, user, xb);
  convw_kernel<<<16384 / 256, 256, 0, stream>>>(Wl1, Wr1, Wl2, Wr2, Wf1, Wf2);
  gather1_kernel<<<NN * 16 / 256, 256, 0, stream>>>(rowptr, esrc, xb, aggb);
  fused_mfma_kernel<<<(NN + MBLK - 1) / MBLK, 512, 0, stream>>>(
      xb, aggb, Wf1, bl1, Wf2, bl2);
  gather2_kernel<<<NN * 16 / 256, 256, 0, stream>>>(rowptr, esrc, hWb, xb, dref);
  scatter2_kernel<<<(NE + 255) / 256, 256, 0, stream>>>(src, dst, rowptr, cnt, epk);
  score_kernel<<<NN * 16 / 256, 256, 0, stream>>>(rowptr, epk, xb, out);
}

// Round 6
// 405.371 us; speedup vs baseline: 1.0331x; 1.0331x over previous
//
#include <hip/hip_runtime.h>

#define NMOV 100000
#define NUSR 50000
#define NN   150000
#define DIM  128
#define HID  256
#define NE   500000

#define MBLK 128           // rows per block
#define LDK  264           // LDS row stride in shorts for the A/h tile
#define NB_SCAN ((NN + 255) / 256)   // 586
#define NB_DEG  ((NE + 255) / 256)   // 1954
#define NB_CVX  (NN * DIM / 8 / 256) // 9375
#define NB_CVW  64

typedef __attribute__((ext_vector_type(8))) short bf16x8;
typedef __attribute__((ext_vector_type(4))) float f32x4;

__device__ __forceinline__ short f2bf(float f) {
  union { float f; unsigned u; } v; v.f = f;
  unsigned r = (v.u + 0x7fffu + ((v.u >> 16) & 1u)) >> 16;   // RNE
  return (short)r;
}
__device__ __forceinline__ float bf2f(short s) {
  union { unsigned u; float f; } v;
  v.u = ((unsigned)(unsigned short)s) << 16;
  return v.f;
}

// ================= prep: deg + convx + convw merged (block-range split) =========
__global__ __launch_bounds__(256) void prep_kernel(
    const int* __restrict__ dst, int* __restrict__ degi,
    const float* __restrict__ movie, const float* __restrict__ user,
    short* __restrict__ xb,
    const float* __restrict__ Wl1, const float* __restrict__ Wr1,
    const float* __restrict__ Wl2, const float* __restrict__ Wr2,
    short* __restrict__ Wf1, short* __restrict__ Wf2) {
  int blk = blockIdx.x;
  int tid = threadIdx.x;
  if (blk < NB_DEG) {
    int e = blk * 256 + tid;
    if (e < NE) atomicAdd(&degi[dst[e]], 1);
    return;
  }
  blk -= NB_DEG;
  if (blk < NB_CVX) {
    int c = blk * 256 + tid;                       // chunk of 8
    size_t base = (size_t)c * 8;
    const float* srcp = (base < (size_t)NMOV * DIM) ? (movie + base)
                                                    : (user + (base - (size_t)NMOV * DIM));
    float4 v0 = ((const float4*)srcp)[0];
    float4 v1 = ((const float4*)srcp)[1];
    short4 s0 = make_short4(f2bf(v0.x), f2bf(v0.y), f2bf(v0.z), f2bf(v0.w));
    short4 s1 = make_short4(f2bf(v1.x), f2bf(v1.y), f2bf(v1.z), f2bf(v1.w));
    *(short4*)(xb + base)     = s0;
    *(short4*)(xb + base + 4) = s1;
    return;
  }
  blk -= NB_CVX;
  {
    int t = blk * 256 + tid;   // 2*16*8*64 = 16384 threads
    int stage = t >> 13;
    int r = t & 8191;
    int n    = r >> 9;
    int kk   = (r >> 6) & 7;
    int lane = r & 63;
    int ncol  = n * 16 + (lane & 15);
    int kbase = kk * 32 + (lane >> 4) * 8;
    short vals[8];
#pragma unroll
    for (int jj = 0; jj < 8; jj++) {
      int k = kbase + jj;
      float v;
      if (stage == 0)
        v = (k < 128) ? Wl1[(size_t)k * HID + ncol] : Wr1[(size_t)(k - 128) * HID + ncol];
      else
        v = (ncol < 128) ? Wl2[(size_t)k * DIM + ncol] : Wr2[(size_t)k * DIM + (ncol - 128)];
      vals[jj] = f2bf(v);
    }
    short* outp = (stage == 0 ? Wf1 : Wf2) + ((size_t)(n * 8 + kk) << 9) + lane * 8;
    *(short4*)(outp)     = make_short4(vals[0], vals[1], vals[2], vals[3]);
    *(short4*)(outp + 4) = make_short4(vals[4], vals[5], vals[6], vals[7]);
  }
}

// ================= CSR scans =================
__global__ __launch_bounds__(256) void scan1_kernel(const int* __restrict__ degi,
                                                    int* __restrict__ pre,
                                                    int* __restrict__ bsum) {
  __shared__ int s[256];
  int tid = threadIdx.x;
  int i = blockIdx.x * 256 + tid;
  int v = (i < NN) ? degi[i] : 0;
  s[tid] = v;
  __syncthreads();
#pragma unroll
  for (int off = 1; off < 256; off <<= 1) {
    int t = (tid >= off) ? s[tid - off] : 0;
    __syncthreads();
    s[tid] += t;
    __syncthreads();
  }
  if (i < NN) pre[i] = s[tid] - v;
  if (tid == 255) bsum[blockIdx.x] = s[255];
}

// merged scan2+scan3: each block reduces its own bsum prefix, then writes rowptr
__global__ __launch_bounds__(256) void scan23_kernel(const int* __restrict__ pre,
                                                     const int* __restrict__ bsum,
                                                     int* __restrict__ rowptr) {
  __shared__ int sm[256];
  int tid = threadIdx.x;
  int nb = blockIdx.x;
  int v = 0;
  for (int i = tid; i < nb; i += 256) v += bsum[i];   // <=3 iters
  sm[tid] = v;
  __syncthreads();
#pragma unroll
  for (int off = 128; off > 0; off >>= 1) {
    if (tid < off) sm[tid] += sm[tid + off];
    __syncthreads();
  }
  int base = sm[0];
  int i = nb * 256 + tid;
  if (i < NN) rowptr[i] = pre[i] + base;
  if (i == 0) rowptr[NN] = NE;
}

// stores SRC node id per CSR slot (single indirection in the gathers)
__global__ __launch_bounds__(256) void csr_scatter_kernel(const int* __restrict__ src,
                                                          const int* __restrict__ dst,
                                                          const int* __restrict__ rowptr,
                                                          int* __restrict__ cnt,
                                                          int* __restrict__ esrc) {
  int e = blockIdx.x * 256 + threadIdx.x;
  if (e >= NE) return;
  int d = dst[e];
  int pos = rowptr[d] + atomicAdd(&cnt[d], 1);
  esrc[pos] = src[e];
}

// ================= fused MFMA: gather1 + both GEMMs, h stays in LDS =================
// Staging does the neighbor-mean gather IN-KERNEL (gather1 eliminated; aggb
// never materialized). xb is strictly read-only here (other blocks gather
// random xb rows). Outputs: hW half staged->coalesced bf16 to hW_out;
// partial half (h@Wr2+bl2) stored direct as f32 to dref (64B-line coalesced).
__global__ __launch_bounds__(512, 4) void fused_mfma_kernel(
    const int* __restrict__ rowptr, const int* __restrict__ esrc,
    const short* __restrict__ xb, short* __restrict__ hW_out,
    const short* __restrict__ Wf1, const float* __restrict__ bl1,
    const short* __restrict__ Wf2, const float* __restrict__ bl2,
    float* __restrict__ dref) {
  __shared__ __align__(16) short tile[MBLK][LDK];   // 67.6 KB -> 2 blocks/CU
  const int tid = threadIdx.x;
  const int row0 = blockIdx.x * MBLK;

  // ---- staging: A_cat = [mean_gather(xb) | xb_own] per row, 16-lane groups ----
  {
    const int grp = tid >> 4;        // 0..31
    const int l   = tid & 15;
    for (int rr = grp; rr < MBLK; rr += 32) {
      int row = row0 + rr;
      if (row < NN) {
        bf16x8 xv = *(const bf16x8*)(xb + (size_t)row * DIM + l * 8);
        *(bf16x8*)&tile[rr][DIM + l * 8] = xv;
        int b = rowptr[row], e = rowptr[row + 1];
        float acc[8] = {0.f, 0.f, 0.f, 0.f, 0.f, 0.f, 0.f, 0.f};
        for (int j = b; j < e; j += 4) {
          int i1 = (j + 1 < e) ? j + 1 : j;
          int i2 = (j + 2 < e) ? j + 2 : j;
          int i3 = (j + 3 < e) ? j + 3 : j;
          int s0 = esrc[j], s1 = esrc[i1], s2 = esrc[i2], s3 = esrc[i3];
          bf16x8 r0 = *(const bf16x8*)(xb + (size_t)s0 * DIM + l * 8);
          bf16x8 r1 = *(const bf16x8*)(xb + (size_t)s1 * DIM + l * 8);
          bf16x8 r2 = *(const bf16x8*)(xb + (size_t)s2 * DIM + l * 8);
          bf16x8 r3 = *(const bf16x8*)(xb + (size_t)s3 * DIM + l * 8);
          float m1 = (j + 1 < e) ? 1.f : 0.f;
          float m2 = (j + 2 < e) ? 1.f : 0.f;
          float m3 = (j + 3 < e) ? 1.f : 0.f;
#pragma unroll
          for (int k = 0; k < 8; k++)
            acc[k] += bf2f(r0[k]) + m1 * bf2f(r1[k]) + m2 * bf2f(r2[k]) + m3 * bf2f(r3[k]);
        }
        float inv = 1.0f / fmaxf((float)(e - b), 1.0f);
        bf16x8 ov;
#pragma unroll
        for (int k = 0; k < 8; k++) ov[k] = f2bf(acc[k] * inv);
        *(bf16x8*)&tile[rr][l * 8] = ov;
      } else {
        bf16x8 z = {0, 0, 0, 0, 0, 0, 0, 0};
        *(bf16x8*)&tile[rr][l * 8] = z;
        *(bf16x8*)&tile[rr][DIM + l * 8] = z;
      }
    }
  }
  __syncthreads();

  const int lane = tid & 63;
  const int wv   = tid >> 6;          // 0..7
  const int c    = lane & 15;
  const int quad = lane >> 4;
  const int wrow = (wv & 3) * 32;     // row quarter (32 rows = 2 groups of 16)
  const int ch   = wv >> 2;           // col half

  // ---- stage 1: h = relu(A_cat @ W1 + bl1) -> LDS ----
  {
    bf16x8 af[2][8];
#pragma unroll
    for (int rg = 0; rg < 2; rg++)
#pragma unroll
      for (int kk = 0; kk < 8; kk++)
        af[rg][kk] = *(const bf16x8*)&tile[wrow + rg * 16 + c][kk * 32 + quad * 8];
    __syncthreads();                  // A in regs everywhere -> safe to overwrite tile

#pragma unroll 2
    for (int nn = 0; nn < 8; nn++) {
      int n = ch * 8 + nn;
      const short* wq = Wf1 + ((size_t)(n * 8) << 9) + lane * 8;
      bf16x8 bw[8];
#pragma unroll
      for (int kk = 0; kk < 8; kk++)
        bw[kk] = *(const bf16x8*)(wq + ((size_t)kk << 9));
      f32x4 a0 = {0.f, 0.f, 0.f, 0.f}, a1 = {0.f, 0.f, 0.f, 0.f};
      __builtin_amdgcn_s_setprio(1);
#pragma unroll
      for (int kk = 0; kk < 8; kk++) {
        a0 = __builtin_amdgcn_mfma_f32_16x16x32_bf16(af[0][kk], bw[kk], a0, 0, 0, 0);
        a1 = __builtin_amdgcn_mfma_f32_16x16x32_bf16(af[1][kk], bw[kk], a1, 0, 0, 0);
      }
      __builtin_amdgcn_s_setprio(0);
      float bv = bl1[n * 16 + c];
#pragma unroll
      for (int i = 0; i < 4; i++) {
        tile[wrow +      quad * 4 + i][n * 16 + c] = f2bf(fmaxf(a0[i] + bv, 0.0f));
        tile[wrow + 16 + quad * 4 + i][n * 16 + c] = f2bf(fmaxf(a1[i] + bv, 0.0f));
      }
    }
  }
  __syncthreads();

  // ---- stage 2: hW (ch=0) staged in tile; partial+bl2 (ch=1) direct f32 ----
  {
    bf16x8 af[2][8];
#pragma unroll
    for (int rg = 0; rg < 2; rg++)
#pragma unroll
      for (int kk = 0; kk < 8; kk++)
        af[rg][kk] = *(const bf16x8*)&tile[wrow + rg * 16 + c][kk * 32 + quad * 8];
    __syncthreads();                   // all waves done reading h -> safe to overwrite

#pragma unroll 2
    for (int nn = 0; nn < 8; nn++) {
      int n = ch * 8 + nn;
      const short* wq = Wf2 + ((size_t)(n * 8) << 9) + lane * 8;
      bf16x8 bw[8];
#pragma unroll
      for (int kk = 0; kk < 8; kk++)
        bw[kk] = *(const bf16x8*)(wq + ((size_t)kk << 9));
      f32x4 a0 = {0.f, 0.f, 0.f, 0.f}, a1 = {0.f, 0.f, 0.f, 0.f};
      __builtin_amdgcn_s_setprio(1);
#pragma unroll
      for (int kk = 0; kk < 8; kk++) {
        a0 = __builtin_amdgcn_mfma_f32_16x16x32_bf16(af[0][kk], bw[kk], a0, 0, 0, 0);
        a1 = __builtin_amdgcn_mfma_f32_16x16x32_bf16(af[1][kk], bw[kk], a1, 0, 0, 0);
      }
      __builtin_amdgcn_s_setprio(0);
      int col = n * 16 + c;
      if (ch == 0) {                   // wave-uniform branch: stage hW bf16
#pragma unroll
        for (int i = 0; i < 4; i++) {
          tile[wrow +      quad * 4 + i][col] = f2bf(a0[i]);
          tile[wrow + 16 + quad * 4 + i][col] = f2bf(a1[i]);
        }
      } else {                         // direct f32 stores (64B-line coalesced)
        float bv = bl2[col - 128];
#pragma unroll
        for (int i = 0; i < 4; i++) {
          int r0i = row0 + wrow + quad * 4 + i;
          if (r0i < NN)      dref[(size_t)r0i * DIM + (col - 128)]        = a0[i] + bv;
          if (r0i + 16 < NN) dref[(size_t)(r0i + 16) * DIM + (col - 128)] = a1[i] + bv;
        }
      }
    }
  }
  __syncthreads();

  // stream hW half out coalesced (16 int4 chunks per row)
  for (int idx = tid; idx < MBLK * 16; idx += 512) {
    int r  = idx >> 4;
    int c8 = idx & 15;
    int row = row0 + r;
    if (row < NN) {
      int4 v = *(const int4*)&tile[r][c8 * 8];
      *(int4*)(hW_out + (size_t)row * DIM + c8 * 8) = v;
    }
  }
}

// ================= gather2: dref += mean(hWb[src]) (own-row f32 RMW); bf16 shadow ====
__global__ __launch_bounds__(256) void gather2_kernel(const int* __restrict__ rowptr,
                                                      const int* __restrict__ esrc,
                                                      const short* __restrict__ hWb,
                                                      short* __restrict__ drefb,
                                                      float* __restrict__ dref) {
  int t = blockIdx.x * 256 + threadIdx.x;
  int node = t >> 4, l = t & 15;
  if (node >= NN) return;
  int b = rowptr[node], e = rowptr[node + 1];
  // hoisted partial (f32, coalesced own-row read)
  float* dr = dref + (size_t)node * DIM + l * 8;
  float4 p0 = *(float4*)(dr);
  float4 p1 = *(float4*)(dr + 4);
  float acc[8] = {0.f, 0.f, 0.f, 0.f, 0.f, 0.f, 0.f, 0.f};
  for (int j = b; j < e; j += 4) {
    int i1 = (j + 1 < e) ? j + 1 : j;
    int i2 = (j + 2 < e) ? j + 2 : j;
    int i3 = (j + 3 < e) ? j + 3 : j;
    int s0 = esrc[j], s1 = esrc[i1], s2 = esrc[i2], s3 = esrc[i3];
    bf16x8 r0 = *(const bf16x8*)(hWb + (size_t)s0 * DIM + l * 8);
    bf16x8 r1 = *(const bf16x8*)(hWb + (size_t)s1 * DIM + l * 8);
    bf16x8 r2 = *(const bf16x8*)(hWb + (size_t)s2 * DIM + l * 8);
    bf16x8 r3 = *(const bf16x8*)(hWb + (size_t)s3 * DIM + l * 8);
    float m1 = (j + 1 < e) ? 1.f : 0.f;
    float m2 = (j + 2 < e) ? 1.f : 0.f;
    float m3 = (j + 3 < e) ? 1.f : 0.f;
#pragma unroll
    for (int k = 0; k < 8; k++)
      acc[k] += bf2f(r0[k]) + m1 * bf2f(r1[k]) + m2 * bf2f(r2[k]) + m3 * bf2f(r3[k]);
  }
  float inv = 1.0f / fmaxf((float)(e - b), 1.0f);
  float fin[8] = {p0.x, p0.y, p0.z, p0.w, p1.x, p1.y, p1.z, p1.w};
  bf16x8 ov;
#pragma unroll
  for (int k = 0; k < 8; k++) {
    fin[k] += acc[k] * inv;
    ov[k] = f2bf(fin[k]);
  }
  *(float4*)(dr)     = make_float4(fin[0], fin[1], fin[2], fin[3]);
  *(float4*)(dr + 4) = make_float4(fin[4], fin[5], fin[6], fin[7]);
  *(bf16x8*)(drefb + (size_t)node * DIM + l * 8) = ov;
}

// ================= edge scoring from bf16 shadow (edge-parallel) =================
__global__ __launch_bounds__(256) void score_kernel(const int* __restrict__ src,
                                                    const int* __restrict__ dst,
                                                    const short* __restrict__ drefb,
                                                    float* __restrict__ out) {
  int t = blockIdx.x * 256 + threadIdx.x;
  int e = t >> 4, l = t & 15;
  if (e >= NE) return;
  int s = src[e], d = dst[e];
  bf16x8 a = *(const bf16x8*)(drefb + (size_t)s * DIM + l * 8);
  bf16x8 b = *(const bf16x8*)(drefb + (size_t)d * DIM + l * 8);
  float sum = 0.f;
#pragma unroll
  for (int k = 0; k < 8; k++) sum += bf2f(a[k]) * bf2f(b[k]);
#pragma unroll
  for (int off = 1; off < 16; off <<= 1) sum += __shfl_xor(sum, off, 16);
  if (l == 0) out[e] = sum;
}

extern "C" void kernel_launch(void* const* d_in, const int* in_sizes, int n_in,
                              void* d_out, int out_size, void* d_ws, size_t ws_size,
                              hipStream_t stream) {
  const int* ei    = (const int*)d_in[0];
  const int* src   = ei;
  const int* dst   = ei + NE;
  // d_in[1] = edge_attr (unused by the reference)
  const float* movie = (const float*)d_in[2];
  const float* user  = (const float*)d_in[3];
  const float* Wl1   = (const float*)d_in[4];
  const float* bl1   = (const float*)d_in[5];
  const float* Wr1   = (const float*)d_in[6];
  const float* Wl2   = (const float*)d_in[7];
  const float* bl2   = (const float*)d_in[8];
  const float* Wr2   = (const float*)d_in[9];

  float* out  = (float*)d_out;       // [NE] ratings
  float* dref = out + NE;            // [NN*DIM] refined (f32 output)

  // workspace (~81.6 MB): ints | xb(+drefb alias) | hWb | Wf1 | Wf2
  int* degi   = (int*)d_ws;                    // [NN] (zeroed)
  int* cnt    = degi + NN;                     // [NN] (zeroed)
  int* pre    = cnt + NN;                      // [NN]
  int* bsum   = pre + NN;                      // [1024]
  int* rowptr = bsum + 1024;                   // [NN+1]
  int* esrc   = rowptr + NN + 1;               // [NE] src node per CSR slot
  short* xb   = (short*)(((uintptr_t)(esrc + NE) + 15) & ~(uintptr_t)15);  // [NN*DIM] bf16
  short* hWb  = xb + (size_t)NN * DIM;         // [NN*DIM] bf16 (h@Wl2, from fused)
  short* Wf1  = hWb + (size_t)NN * DIM;        // [65536]
  short* Wf2  = Wf1 + 65536;                   // [65536]
  short* drefb = xb;                           // alias: xb dead after fused

  hipMemsetAsync(degi, 0, (size_t)2 * NN * sizeof(int), stream);

  prep_kernel<<<NB_DEG + NB_CVX + NB_CVW, 256, 0, stream>>>(
      dst, degi, movie, user, xb, Wl1, Wr1, Wl2, Wr2, Wf1, Wf2);
  scan1_kernel<<<NB_SCAN, 256, 0, stream>>>(degi, pre, bsum);
  scan23_kernel<<<NB_SCAN, 256, 0, stream>>>(pre, bsum, rowptr);
  csr_scatter_kernel<<<(NE + 255) / 256, 256, 0, stream>>>(src, dst, rowptr, cnt, esrc);
  fused_mfma_kernel<<<(NN + MBLK - 1) / MBLK, 512, 0, stream>>>(
      rowptr, esrc, xb, hWb, Wf1, bl1, Wf2, bl2, dref);
  gather2_kernel<<<NN * 16 / 256, 256, 0, stream>>>(rowptr, esrc, hWb, drefb, dref);
  score_kernel<<<NE * 16 / 256, 256, 0, stream>>>(src, dst, drefb, out);
}

// Round 7
// 401.426 us; speedup vs baseline: 1.0433x; 1.0098x over previous
//
#include <hip/hip_runtime.h>

#define NMOV 100000
#define NUSR 50000
#define NN   150000
#define DIM  128
#define HID  256
#define NE   500000

#define MBLK 128           // rows per block
#define LDK  264           // LDS row stride in shorts for the A/h tile
#define NB_SCAN ((NN + 255) / 256)   // 586
#define NB_DEG  ((NE + 255) / 256)   // 1954
#define NB_CVX  (NN * DIM / 8 / 256) // 9375
#define NB_CVW  64

typedef __attribute__((ext_vector_type(8))) short bf16x8;
typedef __attribute__((ext_vector_type(4))) float f32x4;

__device__ __forceinline__ short f2bf(float f) {
  union { float f; unsigned u; } v; v.f = f;
  unsigned r = (v.u + 0x7fffu + ((v.u >> 16) & 1u)) >> 16;   // RNE
  return (short)r;
}
__device__ __forceinline__ float bf2f(short s) {
  union { unsigned u; float f; } v;
  v.u = ((unsigned)(unsigned short)s) << 16;
  return v.f;
}

// ================= prep: deg + convx + convw merged (block-range split) =========
__global__ __launch_bounds__(256) void prep_kernel(
    const int* __restrict__ dst, int* __restrict__ degi,
    const float* __restrict__ movie, const float* __restrict__ user,
    short* __restrict__ xb,
    const float* __restrict__ Wl1, const float* __restrict__ Wr1,
    const float* __restrict__ Wl2, const float* __restrict__ Wr2,
    short* __restrict__ Wf1, short* __restrict__ Wf2) {
  int blk = blockIdx.x;
  int tid = threadIdx.x;
  if (blk < NB_DEG) {
    int e = blk * 256 + tid;
    if (e < NE) atomicAdd(&degi[dst[e]], 1);
    return;
  }
  blk -= NB_DEG;
  if (blk < NB_CVX) {
    int c = blk * 256 + tid;                       // chunk of 8
    size_t base = (size_t)c * 8;
    const float* srcp = (base < (size_t)NMOV * DIM) ? (movie + base)
                                                    : (user + (base - (size_t)NMOV * DIM));
    float4 v0 = ((const float4*)srcp)[0];
    float4 v1 = ((const float4*)srcp)[1];
    short4 s0 = make_short4(f2bf(v0.x), f2bf(v0.y), f2bf(v0.z), f2bf(v0.w));
    short4 s1 = make_short4(f2bf(v1.x), f2bf(v1.y), f2bf(v1.z), f2bf(v1.w));
    *(short4*)(xb + base)     = s0;
    *(short4*)(xb + base + 4) = s1;
    return;
  }
  blk -= NB_CVX;
  {
    int t = blk * 256 + tid;   // 2*16*8*64 = 16384 threads
    int stage = t >> 13;
    int r = t & 8191;
    int n    = r >> 9;
    int kk   = (r >> 6) & 7;
    int lane = r & 63;
    int ncol  = n * 16 + (lane & 15);
    int kbase = kk * 32 + (lane >> 4) * 8;
    short vals[8];
#pragma unroll
    for (int jj = 0; jj < 8; jj++) {
      int k = kbase + jj;
      float v;
      if (stage == 0)
        v = (k < 128) ? Wl1[(size_t)k * HID + ncol] : Wr1[(size_t)(k - 128) * HID + ncol];
      else
        v = (ncol < 128) ? Wl2[(size_t)k * DIM + ncol] : Wr2[(size_t)k * DIM + (ncol - 128)];
      vals[jj] = f2bf(v);
    }
    short* outp = (stage == 0 ? Wf1 : Wf2) + ((size_t)(n * 8 + kk) << 9) + lane * 8;
    *(short4*)(outp)     = make_short4(vals[0], vals[1], vals[2], vals[3]);
    *(short4*)(outp + 4) = make_short4(vals[4], vals[5], vals[6], vals[7]);
  }
}

// ================= CSR scans =================
__global__ __launch_bounds__(256) void scan1_kernel(const int* __restrict__ degi,
                                                    int* __restrict__ pre,
                                                    int* __restrict__ bsum) {
  __shared__ int s[256];
  int tid = threadIdx.x;
  int i = blockIdx.x * 256 + tid;
  int v = (i < NN) ? degi[i] : 0;
  s[tid] = v;
  __syncthreads();
#pragma unroll
  for (int off = 1; off < 256; off <<= 1) {
    int t = (tid >= off) ? s[tid - off] : 0;
    __syncthreads();
    s[tid] += t;
    __syncthreads();
  }
  if (i < NN) pre[i] = s[tid] - v;
  if (tid == 255) bsum[blockIdx.x] = s[255];
}

// merged scan2+scan3: each block reduces its own bsum prefix, then writes rowptr
__global__ __launch_bounds__(256) void scan23_kernel(const int* __restrict__ pre,
                                                     const int* __restrict__ bsum,
                                                     int* __restrict__ rowptr) {
  __shared__ int sm[256];
  int tid = threadIdx.x;
  int nb = blockIdx.x;
  int v = 0;
  for (int i = tid; i < nb; i += 256) v += bsum[i];   // <=3 iters
  sm[tid] = v;
  __syncthreads();
#pragma unroll
  for (int off = 128; off > 0; off >>= 1) {
    if (tid < off) sm[tid] += sm[tid + off];
    __syncthreads();
  }
  int base = sm[0];
  int i = nb * 256 + tid;
  if (i < NN) rowptr[i] = pre[i] + base;
  if (i == 0) rowptr[NN] = NE;
}

// stores (src, edge_id) per CSR slot — single pass, feeds gathers (.x) AND score (.y)
__global__ __launch_bounds__(256) void csr_scatter_kernel(const int* __restrict__ src,
                                                          const int* __restrict__ dst,
                                                          const int* __restrict__ rowptr,
                                                          int* __restrict__ cnt,
                                                          int2* __restrict__ epk) {
  int e = blockIdx.x * 256 + threadIdx.x;
  if (e >= NE) return;
  int d = dst[e];
  int pos = rowptr[d] + atomicAdd(&cnt[d], 1);
  epk[pos] = make_int2(src[e], e);
}

// ================= fused MFMA: gather1 + both GEMMs, h stays in LDS =================
// Staging does the neighbor-mean gather IN-KERNEL. xb strictly read-only here.
// Outputs: hW half staged->coalesced bf16 to hW_out; partial half (h@Wr2+bl2)
// stored direct as f32 to dref (64B-line coalesced).
__global__ __launch_bounds__(512, 4) void fused_mfma_kernel(
    const int* __restrict__ rowptr, const int2* __restrict__ epk,
    const short* __restrict__ xb, short* __restrict__ hW_out,
    const short* __restrict__ Wf1, const float* __restrict__ bl1,
    const short* __restrict__ Wf2, const float* __restrict__ bl2,
    float* __restrict__ dref) {
  __shared__ __align__(16) short tile[MBLK][LDK];   // 67.6 KB -> 2 blocks/CU
  const int tid = threadIdx.x;
  const int row0 = blockIdx.x * MBLK;

  // ---- staging: A_cat = [mean_gather(xb) | xb_own] per row, 16-lane groups ----
  {
    const int grp = tid >> 4;        // 0..31
    const int l   = tid & 15;
    for (int rr = grp; rr < MBLK; rr += 32) {
      int row = row0 + rr;
      if (row < NN) {
        bf16x8 xv = *(const bf16x8*)(xb + (size_t)row * DIM + l * 8);
        *(bf16x8*)&tile[rr][DIM + l * 8] = xv;
        int b = rowptr[row], e = rowptr[row + 1];
        float acc[8] = {0.f, 0.f, 0.f, 0.f, 0.f, 0.f, 0.f, 0.f};
        for (int j = b; j < e; j += 4) {
          int i1 = (j + 1 < e) ? j + 1 : j;
          int i2 = (j + 2 < e) ? j + 2 : j;
          int i3 = (j + 3 < e) ? j + 3 : j;
          int s0 = epk[j].x, s1 = epk[i1].x, s2 = epk[i2].x, s3 = epk[i3].x;
          bf16x8 r0 = *(const bf16x8*)(xb + (size_t)s0 * DIM + l * 8);
          bf16x8 r1 = *(const bf16x8*)(xb + (size_t)s1 * DIM + l * 8);
          bf16x8 r2 = *(const bf16x8*)(xb + (size_t)s2 * DIM + l * 8);
          bf16x8 r3 = *(const bf16x8*)(xb + (size_t)s3 * DIM + l * 8);
          float m1 = (j + 1 < e) ? 1.f : 0.f;
          float m2 = (j + 2 < e) ? 1.f : 0.f;
          float m3 = (j + 3 < e) ? 1.f : 0.f;
#pragma unroll
          for (int k = 0; k < 8; k++)
            acc[k] += bf2f(r0[k]) + m1 * bf2f(r1[k]) + m2 * bf2f(r2[k]) + m3 * bf2f(r3[k]);
        }
        float inv = 1.0f / fmaxf((float)(e - b), 1.0f);
        bf16x8 ov;
#pragma unroll
        for (int k = 0; k < 8; k++) ov[k] = f2bf(acc[k] * inv);
        *(bf16x8*)&tile[rr][l * 8] = ov;
      } else {
        bf16x8 z = {0, 0, 0, 0, 0, 0, 0, 0};
        *(bf16x8*)&tile[rr][l * 8] = z;
        *(bf16x8*)&tile[rr][DIM + l * 8] = z;
      }
    }
  }
  __syncthreads();

  const int lane = tid & 63;
  const int wv   = tid >> 6;          // 0..7
  const int c    = lane & 15;
  const int quad = lane >> 4;
  const int wrow = (wv & 3) * 32;     // row quarter (32 rows = 2 groups of 16)
  const int ch   = wv >> 2;           // col half

  // ---- stage 1: h = relu(A_cat @ W1 + bl1) -> LDS ----
  {
    bf16x8 af[2][8];
#pragma unroll
    for (int rg = 0; rg < 2; rg++)
#pragma unroll
      for (int kk = 0; kk < 8; kk++)
        af[rg][kk] = *(const bf16x8*)&tile[wrow + rg * 16 + c][kk * 32 + quad * 8];
    __syncthreads();                  // A in regs everywhere -> safe to overwrite tile

#pragma unroll 2
    for (int nn = 0; nn < 8; nn++) {
      int n = ch * 8 + nn;
      const short* wq = Wf1 + ((size_t)(n * 8) << 9) + lane * 8;
      bf16x8 bw[8];
#pragma unroll
      for (int kk = 0; kk < 8; kk++)
        bw[kk] = *(const bf16x8*)(wq + ((size_t)kk << 9));
      f32x4 a0 = {0.f, 0.f, 0.f, 0.f}, a1 = {0.f, 0.f, 0.f, 0.f};
      __builtin_amdgcn_s_setprio(1);
#pragma unroll
      for (int kk = 0; kk < 8; kk++) {
        a0 = __builtin_amdgcn_mfma_f32_16x16x32_bf16(af[0][kk], bw[kk], a0, 0, 0, 0);
        a1 = __builtin_amdgcn_mfma_f32_16x16x32_bf16(af[1][kk], bw[kk], a1, 0, 0, 0);
      }
      __builtin_amdgcn_s_setprio(0);
      float bv = bl1[n * 16 + c];
#pragma unroll
      for (int i = 0; i < 4; i++) {
        tile[wrow +      quad * 4 + i][n * 16 + c] = f2bf(fmaxf(a0[i] + bv, 0.0f));
        tile[wrow + 16 + quad * 4 + i][n * 16 + c] = f2bf(fmaxf(a1[i] + bv, 0.0f));
      }
    }
  }
  __syncthreads();

  // ---- stage 2: hW (ch=0) staged in tile; partial+bl2 (ch=1) direct f32 ----
  {
    bf16x8 af[2][8];
#pragma unroll
    for (int rg = 0; rg < 2; rg++)
#pragma unroll
      for (int kk = 0; kk < 8; kk++)
        af[rg][kk] = *(const bf16x8*)&tile[wrow + rg * 16 + c][kk * 32 + quad * 8];
    __syncthreads();                   // all waves done reading h -> safe to overwrite

#pragma unroll 2
    for (int nn = 0; nn < 8; nn++) {
      int n = ch * 8 + nn;
      const short* wq = Wf2 + ((size_t)(n * 8) << 9) + lane * 8;
      bf16x8 bw[8];
#pragma unroll
      for (int kk = 0; kk < 8; kk++)
        bw[kk] = *(const bf16x8*)(wq + ((size_t)kk << 9));
      f32x4 a0 = {0.f, 0.f, 0.f, 0.f}, a1 = {0.f, 0.f, 0.f, 0.f};
      __builtin_amdgcn_s_setprio(1);
#pragma unroll
      for (int kk = 0; kk < 8; kk++) {
        a0 = __builtin_amdgcn_mfma_f32_16x16x32_bf16(af[0][kk], bw[kk], a0, 0, 0, 0);
        a1 = __builtin_amdgcn_mfma_f32_16x16x32_bf16(af[1][kk], bw[kk], a1, 0, 0, 0);
      }
      __builtin_amdgcn_s_setprio(0);
      int col = n * 16 + c;
      if (ch == 0) {                   // wave-uniform branch: stage hW bf16
#pragma unroll
        for (int i = 0; i < 4; i++) {
          tile[wrow +      quad * 4 + i][col] = f2bf(a0[i]);
          tile[wrow + 16 + quad * 4 + i][col] = f2bf(a1[i]);
        }
      } else {                         // direct f32 stores (64B-line coalesced)
        float bv = bl2[col - 128];
#pragma unroll
        for (int i = 0; i < 4; i++) {
          int r0i = row0 + wrow + quad * 4 + i;
          if (r0i < NN)      dref[(size_t)r0i * DIM + (col - 128)]        = a0[i] + bv;
          if (r0i + 16 < NN) dref[(size_t)(r0i + 16) * DIM + (col - 128)] = a1[i] + bv;
        }
      }
    }
  }
  __syncthreads();

  // stream hW half out coalesced (16 int4 chunks per row)
  for (int idx = tid; idx < MBLK * 16; idx += 512) {
    int r  = idx >> 4;
    int c8 = idx & 15;
    int row = row0 + r;
    if (row < NN) {
      int4 v = *(const int4*)&tile[r][c8 * 8];
      *(int4*)(hW_out + (size_t)row * DIM + c8 * 8) = v;
    }
  }
}

// ================= gather2: dref += mean(hWb[src]) (own-row f32 RMW); bf16 shadow ====
__global__ __launch_bounds__(256) void gather2_kernel(const int* __restrict__ rowptr,
                                                      const int2* __restrict__ epk,
                                                      const short* __restrict__ hWb,
                                                      short* __restrict__ drefb,
                                                      float* __restrict__ dref) {
  int t = blockIdx.x * 256 + threadIdx.x;
  int node = t >> 4, l = t & 15;
  if (node >= NN) return;
  int b = rowptr[node], e = rowptr[node + 1];
  // hoisted partial (f32, coalesced own-row read)
  float* dr = dref + (size_t)node * DIM + l * 8;
  float4 p0 = *(float4*)(dr);
  float4 p1 = *(float4*)(dr + 4);
  float acc[8] = {0.f, 0.f, 0.f, 0.f, 0.f, 0.f, 0.f, 0.f};
  for (int j = b; j < e; j += 4) {
    int i1 = (j + 1 < e) ? j + 1 : j;
    int i2 = (j + 2 < e) ? j + 2 : j;
    int i3 = (j + 3 < e) ? j + 3 : j;
    int s0 = epk[j].x, s1 = epk[i1].x, s2 = epk[i2].x, s3 = epk[i3].x;
    bf16x8 r0 = *(const bf16x8*)(hWb + (size_t)s0 * DIM + l * 8);
    bf16x8 r1 = *(const bf16x8*)(hWb + (size_t)s1 * DIM + l * 8);
    bf16x8 r2 = *(const bf16x8*)(hWb + (size_t)s2 * DIM + l * 8);
    bf16x8 r3 = *(const bf16x8*)(hWb + (size_t)s3 * DIM + l * 8);
    float m1 = (j + 1 < e) ? 1.f : 0.f;
    float m2 = (j + 2 < e) ? 1.f : 0.f;
    float m3 = (j + 3 < e) ? 1.f : 0.f;
#pragma unroll
    for (int k = 0; k < 8; k++)
      acc[k] += bf2f(r0[k]) + m1 * bf2f(r1[k]) + m2 * bf2f(r2[k]) + m3 * bf2f(r3[k]);
  }
  float inv = 1.0f / fmaxf((float)(e - b), 1.0f);
  float fin[8] = {p0.x, p0.y, p0.z, p0.w, p1.x, p1.y, p1.z, p1.w};
  bf16x8 ov;
#pragma unroll
  for (int k = 0; k < 8; k++) {
    fin[k] += acc[k] * inv;
    ov[k] = f2bf(fin[k]);
  }
  *(float4*)(dr)     = make_float4(fin[0], fin[1], fin[2], fin[3]);
  *(float4*)(dr + 4) = make_float4(fin[4], fin[5], fin[6], fin[7]);
  *(bf16x8*)(drefb + (size_t)node * DIM + l * 8) = ov;
}

// ================= edge scoring, CSR-node-parallel: dst row register-cached ==========
// One random src-row read per edge (was two); out[eid] scatter write.
__global__ __launch_bounds__(256) void score_kernel(const int* __restrict__ rowptr,
                                                    const int2* __restrict__ epk,
                                                    const short* __restrict__ drefb,
                                                    float* __restrict__ out) {
  int t = blockIdx.x * 256 + threadIdx.x;
  int node = t >> 4, l = t & 15;
  if (node >= NN) return;
  int b = rowptr[node], e = rowptr[node + 1];
  if (b == e) return;
  bf16x8 d = *(const bf16x8*)(drefb + (size_t)node * DIM + l * 8);
  float f[8];
#pragma unroll
  for (int k = 0; k < 8; k++) f[k] = bf2f(d[k]);
  for (int j = b; j < e; j += 4) {
    int i1 = (j + 1 < e) ? j + 1 : j;
    int i2 = (j + 2 < e) ? j + 2 : j;
    int i3 = (j + 3 < e) ? j + 3 : j;
    int2 p0 = epk[j], p1 = epk[i1], p2 = epk[i2], p3 = epk[i3];
    bf16x8 r0 = *(const bf16x8*)(drefb + (size_t)p0.x * DIM + l * 8);
    bf16x8 r1 = *(const bf16x8*)(drefb + (size_t)p1.x * DIM + l * 8);
    bf16x8 r2 = *(const bf16x8*)(drefb + (size_t)p2.x * DIM + l * 8);
    bf16x8 r3 = *(const bf16x8*)(drefb + (size_t)p3.x * DIM + l * 8);
    float s0 = 0.f, s1 = 0.f, s2 = 0.f, s3 = 0.f;
#pragma unroll
    for (int k = 0; k < 8; k++) {
      s0 += bf2f(r0[k]) * f[k];
      s1 += bf2f(r1[k]) * f[k];
      s2 += bf2f(r2[k]) * f[k];
      s3 += bf2f(r3[k]) * f[k];
    }
#pragma unroll
    for (int off = 1; off < 16; off <<= 1) {
      s0 += __shfl_xor(s0, off, 16);
      s1 += __shfl_xor(s1, off, 16);
      s2 += __shfl_xor(s2, off, 16);
      s3 += __shfl_xor(s3, off, 16);
    }
    if (l == 0) {
      out[p0.y] = s0;
      if (j + 1 < e) out[p1.y] = s1;
      if (j + 2 < e) out[p2.y] = s2;
      if (j + 3 < e) out[p3.y] = s3;
    }
  }
}

extern "C" void kernel_launch(void* const* d_in, const int* in_sizes, int n_in,
                              void* d_out, int out_size, void* d_ws, size_t ws_size,
                              hipStream_t stream) {
  const int* ei    = (const int*)d_in[0];
  const int* src   = ei;
  const int* dst   = ei + NE;
  // d_in[1] = edge_attr (unused by the reference)
  const float* movie = (const float*)d_in[2];
  const float* user  = (const float*)d_in[3];
  const float* Wl1   = (const float*)d_in[4];
  const float* bl1   = (const float*)d_in[5];
  const float* Wr1   = (const float*)d_in[6];
  const float* Wl2   = (const float*)d_in[7];
  const float* bl2   = (const float*)d_in[8];
  const float* Wr2   = (const float*)d_in[9];

  float* out  = (float*)d_out;       // [NE] ratings
  float* dref = out + NE;            // [NN*DIM] refined (f32 output)

  // workspace (~84 MB): ints | epk | xb(+drefb alias) | hWb | Wf1 | Wf2
  int* degi   = (int*)d_ws;                    // [NN] (zeroed)
  int* cnt    = degi + NN;                     // [NN] (zeroed)
  int* pre    = cnt + NN;                      // [NN]
  int* bsum   = pre + NN;                      // [1024]
  int* rowptr = bsum + 1024;                   // [NN+1]
  int2* epk   = (int2*)(((uintptr_t)(rowptr + NN + 1) + 7) & ~(uintptr_t)7);  // [NE]
  short* xb   = (short*)(((uintptr_t)(epk + NE) + 15) & ~(uintptr_t)15);  // [NN*DIM] bf16
  short* hWb  = xb + (size_t)NN * DIM;         // [NN*DIM] bf16 (h@Wl2, from fused)
  short* Wf1  = hWb + (size_t)NN * DIM;        // [65536]
  short* Wf2  = Wf1 + 65536;                   // [65536]
  short* drefb = xb;                           // alias: xb dead after fused

  hipMemsetAsync(degi, 0, (size_t)2 * NN * sizeof(int), stream);

  prep_kernel<<<NB_DEG + NB_CVX + NB_CVW, 256, 0, stream>>>(
      dst, degi, movie, user, xb, Wl1, Wr1, Wl2, Wr2, Wf1, Wf2);
  scan1_kernel<<<NB_SCAN, 256, 0, stream>>>(degi, pre, bsum);
  scan23_kernel<<<NB_SCAN, 256, 0, stream>>>(pre, bsum, rowptr);
  csr_scatter_kernel<<<(NE + 255) / 256, 256, 0, stream>>>(src, dst, rowptr, cnt, epk);
  fused_mfma_kernel<<<(NN + MBLK - 1) / MBLK, 512, 0, stream>>>(
      rowptr, epk, xb, hWb, Wf1, bl1, Wf2, bl2, dref);
  gather2_kernel<<<NN * 16 / 256, 256, 0, stream>>>(rowptr, epk, hWb, drefb, dref);
  score_kernel<<<NN * 16 / 256, 256, 0, stream>>>(rowptr, epk, drefb, out);
}

// Round 9
// 376.089 us; speedup vs baseline: 1.1136x; 1.0674x over previous
//
#include <hip/hip_runtime.h>

#define NMOV 100000
#define NUSR 50000
#define NN   150000
#define DIM  128
#define HID  256
#define NE   500000

#define MBLK 128           // rows per block
#define LDK  264           // LDS row stride in shorts for the A/h tile
#define NB_SCAN ((NN + 255) / 256)   // 586
#define NB_DEG  ((NE + 255) / 256)   // 1954
#define NB_CVX  (NN * DIM / 8 / 256) // 9375
#define NB_CVW  64

typedef __attribute__((ext_vector_type(8))) short bf16x8;
typedef __attribute__((ext_vector_type(4))) float f32x4;

__device__ __forceinline__ short f2bf(float f) {
  union { float f; unsigned u; } v; v.f = f;
  unsigned r = (v.u + 0x7fffu + ((v.u >> 16) & 1u)) >> 16;   // RNE
  return (short)r;
}
__device__ __forceinline__ float bf2f(short s) {
  union { unsigned u; float f; } v;
  v.u = ((unsigned)(unsigned short)s) << 16;
  return v.f;
}

// ================= prep: deg + convx + convw merged (block-range split) =========
__global__ __launch_bounds__(256) void prep_kernel(
    const int* __restrict__ dst, int* __restrict__ degi,
    const float* __restrict__ movie, const float* __restrict__ user,
    short* __restrict__ xb,
    const float* __restrict__ Wl1, const float* __restrict__ Wr1,
    const float* __restrict__ Wl2, const float* __restrict__ Wr2,
    short* __restrict__ Wf1, short* __restrict__ Wf2) {
  int blk = blockIdx.x;
  int tid = threadIdx.x;
  if (blk < NB_DEG) {
    int e = blk * 256 + tid;
    if (e < NE) atomicAdd(&degi[dst[e]], 1);
    return;
  }
  blk -= NB_DEG;
  if (blk < NB_CVX) {
    int c = blk * 256 + tid;                       // chunk of 8
    size_t base = (size_t)c * 8;
    const float* srcp = (base < (size_t)NMOV * DIM) ? (movie + base)
                                                    : (user + (base - (size_t)NMOV * DIM));
    float4 v0 = ((const float4*)srcp)[0];
    float4 v1 = ((const float4*)srcp)[1];
    short4 s0 = make_short4(f2bf(v0.x), f2bf(v0.y), f2bf(v0.z), f2bf(v0.w));
    short4 s1 = make_short4(f2bf(v1.x), f2bf(v1.y), f2bf(v1.z), f2bf(v1.w));
    *(short4*)(xb + base)     = s0;
    *(short4*)(xb + base + 4) = s1;
    return;
  }
  blk -= NB_CVX;
  {
    int t = blk * 256 + tid;   // 2*16*8*64 = 16384 threads
    int stage = t >> 13;
    int r = t & 8191;
    int n    = r >> 9;
    int kk   = (r >> 6) & 7;
    int lane = r & 63;
    int ncol  = n * 16 + (lane & 15);
    int kbase = kk * 32 + (lane >> 4) * 8;
    short vals[8];
#pragma unroll
    for (int jj = 0; jj < 8; jj++) {
      int k = kbase + jj;
      float v;
      if (stage == 0)
        v = (k < 128) ? Wl1[(size_t)k * HID + ncol] : Wr1[(size_t)(k - 128) * HID + ncol];
      else
        v = (ncol < 128) ? Wl2[(size_t)k * DIM + ncol] : Wr2[(size_t)k * DIM + (ncol - 128)];
      vals[jj] = f2bf(v);
    }
    short* outp = (stage == 0 ? Wf1 : Wf2) + ((size_t)(n * 8 + kk) << 9) + lane * 8;
    *(short4*)(outp)     = make_short4(vals[0], vals[1], vals[2], vals[3]);
    *(short4*)(outp + 4) = make_short4(vals[4], vals[5], vals[6], vals[7]);
  }
}

// ================= CSR scans =================
__global__ __launch_bounds__(256) void scan1_kernel(const int* __restrict__ degi,
                                                    int* __restrict__ pre,
                                                    int* __restrict__ bsum) {
  __shared__ int s[256];
  int tid = threadIdx.x;
  int i = blockIdx.x * 256 + tid;
  int v = (i < NN) ? degi[i] : 0;
  s[tid] = v;
  __syncthreads();
#pragma unroll
  for (int off = 1; off < 256; off <<= 1) {
    int t = (tid >= off) ? s[tid - off] : 0;
    __syncthreads();
    s[tid] += t;
    __syncthreads();
  }
  if (i < NN) pre[i] = s[tid] - v;
  if (tid == 255) bsum[blockIdx.x] = s[255];
}

// merged scan2+scan3: each block reduces its own bsum prefix, then writes rowptr
__global__ __launch_bounds__(256) void scan23_kernel(const int* __restrict__ pre,
                                                     const int* __restrict__ bsum,
                                                     int* __restrict__ rowptr) {
  __shared__ int sm[256];
  int tid = threadIdx.x;
  int nb = blockIdx.x;
  int v = 0;
  for (int i = tid; i < nb; i += 256) v += bsum[i];   // <=3 iters
  sm[tid] = v;
  __syncthreads();
#pragma unroll
  for (int off = 128; off > 0; off >>= 1) {
    if (tid < off) sm[tid] += sm[tid + off];
    __syncthreads();
  }
  int base = sm[0];
  int i = nb * 256 + tid;
  if (i < NN) rowptr[i] = pre[i] + base;
  if (i == 0) rowptr[NN] = NE;
}

// stores (src, edge_id) per CSR slot — single pass, feeds gathers (.x) AND score (.y)
__global__ __launch_bounds__(256) void csr_scatter_kernel(const int* __restrict__ src,
                                                          const int* __restrict__ dst,
                                                          const int* __restrict__ rowptr,
                                                          int* __restrict__ cnt,
                                                          int2* __restrict__ epk) {
  int e = blockIdx.x * 256 + threadIdx.x;
  if (e >= NE) return;
  int d = dst[e];
  int pos = rowptr[d] + atomicAdd(&cnt[d], 1);
  epk[pos] = make_int2(src[e], e);
}

// ================= fused MFMA: gather1 + both GEMMs, h stays in LDS =================
// Staging does the neighbor-mean gather IN-KERNEL. xb strictly read-only here.
// Stage-2 stages BOTH halves in the tile: cols 0..127 = hW (bf16 -> hW_out),
// cols 128..255 = partial h@Wr2+bl2 (bf16, streamed into the FIRST 256B of each
// node's f32 dref row — gather2 reads it there before overwriting with f32).
__global__ __launch_bounds__(512, 4) void fused_mfma_kernel(
    const int* __restrict__ rowptr, const int2* __restrict__ epk,
    const short* __restrict__ xb, short* __restrict__ hW_out,
    const short* __restrict__ Wf1, const float* __restrict__ bl1,
    const short* __restrict__ Wf2, const float* __restrict__ bl2,
    float* __restrict__ dref) {
  __shared__ __align__(16) short tile[MBLK][LDK];   // 67.6 KB -> 2 blocks/CU
  const int tid = threadIdx.x;
  const int row0 = blockIdx.x * MBLK;

  // ---- staging: A_cat = [mean_gather(xb) | xb_own] per row, 16-lane groups ----
  {
    const int grp = tid >> 4;        // 0..31
    const int l   = tid & 15;
    for (int rr = grp; rr < MBLK; rr += 32) {
      int row = row0 + rr;
      if (row < NN) {
        bf16x8 xv = *(const bf16x8*)(xb + (size_t)row * DIM + l * 8);
        *(bf16x8*)&tile[rr][DIM + l * 8] = xv;
        int b = rowptr[row], e = rowptr[row + 1];
        float acc[8] = {0.f, 0.f, 0.f, 0.f, 0.f, 0.f, 0.f, 0.f};
        for (int j = b; j < e; j += 4) {
          int i1 = (j + 1 < e) ? j + 1 : j;
          int i2 = (j + 2 < e) ? j + 2 : j;
          int i3 = (j + 3 < e) ? j + 3 : j;
          int s0 = epk[j].x, s1 = epk[i1].x, s2 = epk[i2].x, s3 = epk[i3].x;
          bf16x8 r0 = *(const bf16x8*)(xb + (size_t)s0 * DIM + l * 8);
          bf16x8 r1 = *(const bf16x8*)(xb + (size_t)s1 * DIM + l * 8);
          bf16x8 r2 = *(const bf16x8*)(xb + (size_t)s2 * DIM + l * 8);
          bf16x8 r3 = *(const bf16x8*)(xb + (size_t)s3 * DIM + l * 8);
          float m1 = (j + 1 < e) ? 1.f : 0.f;
          float m2 = (j + 2 < e) ? 1.f : 0.f;
          float m3 = (j + 3 < e) ? 1.f : 0.f;
#pragma unroll
          for (int k = 0; k < 8; k++)
            acc[k] += bf2f(r0[k]) + m1 * bf2f(r1[k]) + m2 * bf2f(r2[k]) + m3 * bf2f(r3[k]);
        }
        float inv = 1.0f / fmaxf((float)(e - b), 1.0f);
        bf16x8 ov;
#pragma unroll
        for (int k = 0; k < 8; k++) ov[k] = f2bf(acc[k] * inv);
        *(bf16x8*)&tile[rr][l * 8] = ov;
      } else {
        bf16x8 z = {0, 0, 0, 0, 0, 0, 0, 0};
        *(bf16x8*)&tile[rr][l * 8] = z;
        *(bf16x8*)&tile[rr][DIM + l * 8] = z;
      }
    }
  }
  __syncthreads();

  const int lane = tid & 63;
  const int wv   = tid >> 6;          // 0..7
  const int c    = lane & 15;
  const int quad = lane >> 4;
  const int wrow = (wv & 3) * 32;     // row quarter (32 rows = 2 groups of 16)
  const int ch   = wv >> 2;           // col half

  // ---- stage 1: h = relu(A_cat @ W1 + bl1) -> LDS ----
  {
    bf16x8 af[2][8];
#pragma unroll
    for (int rg = 0; rg < 2; rg++)
#pragma unroll
      for (int kk = 0; kk < 8; kk++)
        af[rg][kk] = *(const bf16x8*)&tile[wrow + rg * 16 + c][kk * 32 + quad * 8];
    __syncthreads();                  // A in regs everywhere -> safe to overwrite tile

#pragma unroll 2
    for (int nn = 0; nn < 8; nn++) {
      int n = ch * 8 + nn;
      const short* wq = Wf1 + ((size_t)(n * 8) << 9) + lane * 8;
      bf16x8 bw[8];
#pragma unroll
      for (int kk = 0; kk < 8; kk++)
        bw[kk] = *(const bf16x8*)(wq + ((size_t)kk << 9));
      f32x4 a0 = {0.f, 0.f, 0.f, 0.f}, a1 = {0.f, 0.f, 0.f, 0.f};
      __builtin_amdgcn_s_setprio(1);
#pragma unroll
      for (int kk = 0; kk < 8; kk++) {
        a0 = __builtin_amdgcn_mfma_f32_16x16x32_bf16(af[0][kk], bw[kk], a0, 0, 0, 0);
        a1 = __builtin_amdgcn_mfma_f32_16x16x32_bf16(af[1][kk], bw[kk], a1, 0, 0, 0);
      }
      __builtin_amdgcn_s_setprio(0);
      float bv = bl1[n * 16 + c];
#pragma unroll
      for (int i = 0; i < 4; i++) {
        tile[wrow +      quad * 4 + i][n * 16 + c] = f2bf(fmaxf(a0[i] + bv, 0.0f));
        tile[wrow + 16 + quad * 4 + i][n * 16 + c] = f2bf(fmaxf(a1[i] + bv, 0.0f));
      }
    }
  }
  __syncthreads();

  // ---- stage 2: [hW | partial+bl2] -> tile (both halves bf16), then stream out ----
  {
    bf16x8 af[2][8];
#pragma unroll
    for (int rg = 0; rg < 2; rg++)
#pragma unroll
      for (int kk = 0; kk < 8; kk++)
        af[rg][kk] = *(const bf16x8*)&tile[wrow + rg * 16 + c][kk * 32 + quad * 8];
    __syncthreads();                   // all waves done reading h -> safe to overwrite

#pragma unroll 2
    for (int nn = 0; nn < 8; nn++) {
      int n = ch * 8 + nn;
      const short* wq = Wf2 + ((size_t)(n * 8) << 9) + lane * 8;
      bf16x8 bw[8];
#pragma unroll
      for (int kk = 0; kk < 8; kk++)
        bw[kk] = *(const bf16x8*)(wq + ((size_t)kk << 9));
      f32x4 a0 = {0.f, 0.f, 0.f, 0.f}, a1 = {0.f, 0.f, 0.f, 0.f};
      __builtin_amdgcn_s_setprio(1);
#pragma unroll
      for (int kk = 0; kk < 8; kk++) {
        a0 = __builtin_amdgcn_mfma_f32_16x16x32_bf16(af[0][kk], bw[kk], a0, 0, 0, 0);
        a1 = __builtin_amdgcn_mfma_f32_16x16x32_bf16(af[1][kk], bw[kk], a1, 0, 0, 0);
      }
      __builtin_amdgcn_s_setprio(0);
      int col = n * 16 + c;
      float bv = (ch == 1) ? bl2[col - 128] : 0.0f;   // bias only on the Wr2 half
#pragma unroll
      for (int i = 0; i < 4; i++) {
        tile[wrow +      quad * 4 + i][col] = f2bf(a0[i] + bv);
        tile[wrow + 16 + quad * 4 + i][col] = f2bf(a1[i] + bv);
      }
    }
  }
  __syncthreads();

  // stream both halves out coalesced: hW -> hW_out; partial bf16 -> first 256B
  // of the node's f32 dref row (gather2 reads it before overwriting with f32)
  for (int idx = tid; idx < MBLK * 32; idx += 512) {
    int r   = idx >> 5;
    int c16 = idx & 31;
    int row = row0 + r;
    if (row < NN) {
      int4 v = *(const int4*)&tile[r][c16 * 8];
      if (c16 < 16)
        *(int4*)(hW_out + (size_t)row * DIM + c16 * 8) = v;
      else
        *(int4*)((short*)(dref + (size_t)row * DIM) + (c16 - 16) * 8) = v;
    }
  }
}

// ================= gather2: dref = partial(bf16, in-row) + mean(hWb[src]) ============
// Reads the bf16 partial from the first 256B of the node's dref row, then
// overwrites the row with the full f32 result. The f32 stores data-depend on
// the partial loads (fin <- p), so the wave drains the reads before writing.
// Also writes the bf16 shadow into drefb (= dead xb).
__global__ __launch_bounds__(256) void gather2_kernel(const int* __restrict__ rowptr,
                                                      const int2* __restrict__ epk,
                                                      const short* __restrict__ hWb,
                                                      short* __restrict__ drefb,
                                                      float* dref) {
  int t = blockIdx.x * 256 + threadIdx.x;
  int node = t >> 4, l = t & 15;
  if (node >= NN) return;
  int b = rowptr[node], e = rowptr[node + 1];
  float* dr = dref + (size_t)node * DIM;
  bf16x8 p = *(const bf16x8*)((const short*)dr + l * 8);   // hoisted bf16 partial
  float acc[8] = {0.f, 0.f, 0.f, 0.f, 0.f, 0.f, 0.f, 0.f};
  for (int j = b; j < e; j += 4) {
    int i1 = (j + 1 < e) ? j + 1 : j;
    int i2 = (j + 2 < e) ? j + 2 : j;
    int i3 = (j + 3 < e) ? j + 3 : j;
    int s0 = epk[j].x, s1 = epk[i1].x, s2 = epk[i2].x, s3 = epk[i3].x;
    bf16x8 r0 = *(const bf16x8*)(hWb + (size_t)s0 * DIM + l * 8);
    bf16x8 r1 = *(const bf16x8*)(hWb + (size_t)s1 * DIM + l * 8);
    bf16x8 r2 = *(const bf16x8*)(hWb + (size_t)s2 * DIM + l * 8);
    bf16x8 r3 = *(const bf16x8*)(hWb + (size_t)s3 * DIM + l * 8);
    float m1 = (j + 1 < e) ? 1.f : 0.f;
    float m2 = (j + 2 < e) ? 1.f : 0.f;
    float m3 = (j + 3 < e) ? 1.f : 0.f;
#pragma unroll
    for (int k = 0; k < 8; k++)
      acc[k] += bf2f(r0[k]) + m1 * bf2f(r1[k]) + m2 * bf2f(r2[k]) + m3 * bf2f(r3[k]);
  }
  float inv = 1.0f / fmaxf((float)(e - b), 1.0f);
  float fin[8];
  bf16x8 ov;
#pragma unroll
  for (int k = 0; k < 8; k++) {
    fin[k] = bf2f(p[k]) + acc[k] * inv;
    ov[k] = f2bf(fin[k]);
  }
  *(float4*)(dr + l * 8)     = make_float4(fin[0], fin[1], fin[2], fin[3]);
  *(float4*)(dr + l * 8 + 4) = make_float4(fin[4], fin[5], fin[6], fin[7]);
  *(bf16x8*)(drefb + (size_t)node * DIM + l * 8) = ov;
}

// ================= edge scoring, CSR-node-parallel: dst row register-cached ==========
__global__ __launch_bounds__(256) void score_kernel(const int* __restrict__ rowptr,
                                                    const int2* __restrict__ epk,
                                                    const short* __restrict__ drefb,
                                                    float* __restrict__ out) {
  int t = blockIdx.x * 256 + threadIdx.x;
  int node = t >> 4, l = t & 15;
  if (node >= NN) return;
  int b = rowptr[node], e = rowptr[node + 1];
  if (b == e) return;
  bf16x8 d = *(const bf16x8*)(drefb + (size_t)node * DIM + l * 8);
  float f[8];
#pragma unroll
  for (int k = 0; k < 8; k++) f[k] = bf2f(d[k]);
  for (int j = b; j < e; j += 4) {
    int i1 = (j + 1 < e) ? j + 1 : j;
    int i2 = (j + 2 < e) ? j + 2 : j;
    int i3 = (j + 3 < e) ? j + 3 : j;
    int2 p0 = epk[j], p1 = epk[i1], p2 = epk[i2], p3 = epk[i3];
    bf16x8 r0 = *(const bf16x8*)(drefb + (size_t)p0.x * DIM + l * 8);
    bf16x8 r1 = *(const bf16x8*)(drefb + (size_t)p1.x * DIM + l * 8);
    bf16x8 r2 = *(const bf16x8*)(drefb + (size_t)p2.x * DIM + l * 8);
    bf16x8 r3 = *(const bf16x8*)(drefb + (size_t)p3.x * DIM + l * 8);
    float s0 = 0.f, s1 = 0.f, s2 = 0.f, s3 = 0.f;
#pragma unroll
    for (int k = 0; k < 8; k++) {
      s0 += bf2f(r0[k]) * f[k];
      s1 += bf2f(r1[k]) * f[k];
      s2 += bf2f(r2[k]) * f[k];
      s3 += bf2f(r3[k]) * f[k];
    }
#pragma unroll
    for (int off = 1; off < 16; off <<= 1) {
      s0 += __shfl_xor(s0, off, 16);
      s1 += __shfl_xor(s1, off, 16);
      s2 += __shfl_xor(s2, off, 16);
      s3 += __shfl_xor(s3, off, 16);
    }
    if (l == 0) {
      out[p0.y] = s0;
      if (j + 1 < e) out[p1.y] = s1;
      if (j + 2 < e) out[p2.y] = s2;
      if (j + 3 < e) out[p3.y] = s3;
    }
  }
}

extern "C" void kernel_launch(void* const* d_in, const int* in_sizes, int n_in,
                              void* d_out, int out_size, void* d_ws, size_t ws_size,
                              hipStream_t stream) {
  const int* ei    = (const int*)d_in[0];
  const int* src   = ei;
  const int* dst   = ei + NE;
  // d_in[1] = edge_attr (unused by the reference)
  const float* movie = (const float*)d_in[2];
  const float* user  = (const float*)d_in[3];
  const float* Wl1   = (const float*)d_in[4];
  const float* bl1   = (const float*)d_in[5];
  const float* Wr1   = (const float*)d_in[6];
  const float* Wl2   = (const float*)d_in[7];
  const float* bl2   = (const float*)d_in[8];
  const float* Wr2   = (const float*)d_in[9];

  float* out  = (float*)d_out;       // [NE] ratings
  float* dref = out + NE;            // [NN*DIM] refined (f32 output; also carries
                                     //   the bf16 partial in each row's first 256B)

  // workspace (~84 MB): ints | epk | xb(+drefb alias) | hWb | Wf1 | Wf2
  int* degi   = (int*)d_ws;                    // [NN] (zeroed)
  int* cnt    = degi + NN;                     // [NN] (zeroed)
  int* pre    = cnt + NN;                      // [NN]
  int* bsum   = pre + NN;                      // [1024]
  int* rowptr = bsum + 1024;                   // [NN+1]
  int2* epk   = (int2*)(((uintptr_t)(rowptr + NN + 1) + 7) & ~(uintptr_t)7);  // [NE]
  short* xb   = (short*)(((uintptr_t)(epk + NE) + 15) & ~(uintptr_t)15);  // [NN*DIM] bf16
  short* hWb  = xb + (size_t)NN * DIM;         // [NN*DIM] bf16 (h@Wl2, from fused)
  short* Wf1  = hWb + (size_t)NN * DIM;        // [65536]
  short* Wf2  = Wf1 + 65536;                   // [65536]
  short* drefb = xb;                           // alias: xb dead after fused

  hipMemsetAsync(degi, 0, (size_t)2 * NN * sizeof(int), stream);

  prep_kernel<<<NB_DEG + NB_CVX + NB_CVW, 256, 0, stream>>>(
      dst, degi, movie, user, xb, Wl1, Wr1, Wl2, Wr2, Wf1, Wf2);
  scan1_kernel<<<NB_SCAN, 256, 0, stream>>>(degi, pre, bsum);
  scan23_kernel<<<NB_SCAN, 256, 0, stream>>>(pre, bsum, rowptr);
  csr_scatter_kernel<<<(NE + 255) / 256, 256, 0, stream>>>(src, dst, rowptr, cnt, epk);
  fused_mfma_kernel<<<(NN + MBLK - 1) / MBLK, 512, 0, stream>>>(
      rowptr, epk, xb, hWb, Wf1, bl1, Wf2, bl2, dref);
  gather2_kernel<<<NN * 16 / 256, 256, 0, stream>>>(rowptr, epk, hWb, drefb, dref);
  score_kernel<<<NN * 16 / 256, 256, 0, stream>>>(rowptr, epk, drefb, out);
}